// Round 3
// baseline (507.166 us; speedup 1.0000x reference)
//
#include <hip/hip_runtime.h>
#include <math.h>

#define NC   1000      // classes
#define DD   4096      // dense dim
#define BB   8192      // batch

#define MAIN_BLOCKS (NC * 4)           // 4 chunks of 1024 d's per class
#define CE_BLOCKS   (BB / 4)           // 4 waves/block, 1 sample/wave
#define TOT_BLOCKS  (MAIN_BLOCKS + CE_BLOCKS)
#define MAXN 128                       // max samples per class (Poisson(8.2), max~20)

// ws: 0: loss1 double | 8: loss2 double | 16: done uint

#define ACC1(xv, yv, acc)                                                     \
    {                                                                         \
        float e = __expf(-fabsf(xv));                                         \
        float inv = __builtin_amdgcn_rcpf(1.f + e);                           \
        acc += (xv >= 0.f) ? inv : e * inv;                                   \
        bce += fmaxf(xv, 0.f) - xv * yv + __logf(1.f + e);                    \
    }

__global__ __launch_bounds__(256) void fused_k(const float* __restrict__ logits,
                                               const float* __restrict__ dense_out,
                                               const int*   __restrict__ target,
                                               const float* __restrict__ dense_labels,
                                               float* __restrict__ out,
                                               double* __restrict__ loss1,
                                               double* __restrict__ loss2,
                                               unsigned* __restrict__ done) {
    int bx = blockIdx.x;
    int t  = threadIdx.x;
    int wave = t >> 6;
    int lane = t & 63;

    __shared__ int   sidx[MAXN];
    __shared__ int   s_n;
    __shared__ float red[4];

    if (bx < MAIN_BLOCKS) {
        // ---------------- main path: one (class, 1024-d chunk) per block ----
        int c     = bx >> 2;
        int chunk = bx & 3;
        int d     = chunk * 1024 + (t << 2);

        if (t == 0) s_n = 0;
        __syncthreads();

        // scan all targets (32 KB, L2-resident) and compact class-c samples
        const int4* tp = (const int4*)target;
        #pragma unroll
        for (int k = 0; k < 8; ++k) {
            int4 v = tp[k * 256 + t];
            int s0 = (k * 256 + t) * 4;
            if (v.x == c) { int p = atomicAdd(&s_n, 1); sidx[p] = s0;     }
            if (v.y == c) { int p = atomicAdd(&s_n, 1); sidx[p] = s0 + 1; }
            if (v.z == c) { int p = atomicAdd(&s_n, 1); sidx[p] = s0 + 2; }
            if (v.w == c) { int p = atomicAdd(&s_n, 1); sidx[p] = s0 + 3; }
        }
        __syncthreads();
        int n = s_n;

        float4 y = *(const float4*)(dense_labels + (size_t)c * DD + d);
        float a0 = 0.f, a1 = 0.f, a2 = 0.f, a3 = 0.f, bce = 0.f;
        const float* dp = dense_out + d;

        if (n > 0) {
            float4 x0 = *(const float4*)(dp + (size_t)sidx[0] * DD);
            int s = 0;
            for (; s + 1 < n; ++s) {
                float4 x1 = *(const float4*)(dp + (size_t)sidx[s + 1] * DD);
                ACC1(x0.x, y.x, a0) ACC1(x0.y, y.y, a1)
                ACC1(x0.z, y.z, a2) ACC1(x0.w, y.w, a3)
                x0 = x1;
            }
            ACC1(x0.x, y.x, a0) ACC1(x0.y, y.y, a1)
            ACC1(x0.z, y.z, a2) ACC1(x0.w, y.w, a3)
        }

        // out+1 is the [NC,DD] segment-sum (4B-aligned only -> dword stores)
        float* p = out + 1 + (size_t)c * DD + d;
        p[0] = a0; p[1] = a1; p[2] = a2; p[3] = a3;

        if (chunk == 0 && t == 0) out[1 + (size_t)NC * DD + c] = (float)n;

        #pragma unroll
        for (int o2 = 32; o2 > 0; o2 >>= 1) bce += __shfl_xor(bce, o2);
        if (lane == 0) red[wave] = bce;
        __syncthreads();
        if (t == 0)
            atomicAdd(loss2, (double)(red[0] + red[1] + red[2] + red[3]));
    } else {
        // ---------------- CE path: 4 waves/block, one sample per wave ------
        int i = (bx - MAIN_BLOCKS) * 4 + wave;
        const float* row = logits + (size_t)i * NC;
        int j0 = lane * 4;

        float4 r0 = *(const float4*)(row + j0);
        float4 r1 = *(const float4*)(row + j0 + 256);
        float4 r2 = *(const float4*)(row + j0 + 512);
        float4 r3;
        if (j0 + 768 < NC) r3 = *(const float4*)(row + j0 + 768);
        else r3 = make_float4(-INFINITY, -INFINITY, -INFINITY, -INFINITY);
        float tl = row[target[i]];

        float mx = fmaxf(fmaxf(fmaxf(r0.x, r0.y), fmaxf(r0.z, r0.w)),
                         fmaxf(fmaxf(r1.x, r1.y), fmaxf(r1.z, r1.w)));
        mx = fmaxf(mx, fmaxf(fmaxf(r2.x, r2.y), fmaxf(r2.z, r2.w)));
        mx = fmaxf(mx, fmaxf(fmaxf(r3.x, r3.y), fmaxf(r3.z, r3.w)));
        #pragma unroll
        for (int o = 32; o > 0; o >>= 1) mx = fmaxf(mx, __shfl_xor(mx, o));

        float s = __expf(r0.x - mx) + __expf(r0.y - mx) + __expf(r0.z - mx) + __expf(r0.w - mx)
                + __expf(r1.x - mx) + __expf(r1.y - mx) + __expf(r1.z - mx) + __expf(r1.w - mx)
                + __expf(r2.x - mx) + __expf(r2.y - mx) + __expf(r2.z - mx) + __expf(r2.w - mx)
                + __expf(r3.x - mx) + __expf(r3.y - mx) + __expf(r3.z - mx) + __expf(r3.w - mx);
        #pragma unroll
        for (int o = 32; o > 0; o >>= 1) s += __shfl_xor(s, o);

        if (lane == 0) red[wave] = -(tl - mx - __logf(s));
        __syncthreads();
        if (t == 0)
            atomicAdd(loss1, (double)(red[0] + red[1] + red[2] + red[3]));
    }

    // ---------------- completion: last block writes the scalar loss --------
    if (t == 0) {
        __threadfence();
        unsigned v = atomicAdd(done, 1u);
        if (v == TOT_BLOCKS - 1u) {
            double l1 = __longlong_as_double(
                __hip_atomic_load((unsigned long long*)loss1,
                                  __ATOMIC_RELAXED, __HIP_MEMORY_SCOPE_AGENT));
            double l2 = __longlong_as_double(
                __hip_atomic_load((unsigned long long*)loss2,
                                  __ATOMIC_RELAXED, __HIP_MEMORY_SCOPE_AGENT));
            out[0] = (float)(0.5 * (l1 / (double)BB) +
                             0.5 * (l2 / ((double)BB * (double)DD)));
        }
    }
}

extern "C" void kernel_launch(void* const* d_in, const int* in_sizes, int n_in,
                              void* d_out, int out_size, void* d_ws, size_t ws_size,
                              hipStream_t stream) {
    const float* logits       = (const float*)d_in[0];
    const float* dense_out    = (const float*)d_in[1];
    const int*   target       = (const int*)d_in[2];
    const float* dense_labels = (const float*)d_in[3];
    float* out = (float*)d_out;

    char* ws = (char*)d_ws;
    double*   loss1 = (double*)(ws + 0);
    double*   loss2 = (double*)(ws + 8);
    unsigned* done  = (unsigned*)(ws + 16);

    hipMemsetAsync(d_ws, 0, 24, stream);

    fused_k<<<TOT_BLOCKS, 256, 0, stream>>>(logits, dense_out, target,
                                            dense_labels, out, loss1, loss2, done);
}

// Round 4
// 251.548 us; speedup vs baseline: 2.0162x; 2.0162x over previous
//
#include <hip/hip_runtime.h>
#include <math.h>

#define NC   1000      // classes
#define DD   4096      // dense dim
#define BB   8192      // batch

#define MAIN_BLOCKS (NC * 4)           // 4 chunks of 1024 d's per class
#define CE_BLOCKS   (BB / 4)           // 4 waves/block, 1 sample/wave
#define TOT_BLOCKS  (MAIN_BLOCKS + CE_BLOCKS)
#define MAXN 128                       // max samples per class (~Poisson(8.2))
#define NSLOT 32                       // loss accumulator slots (contention spread)

// ws: 0: loss1 double[32] | 256: loss2 double[32]   (memset 512 B)

#define ACC1(xv, yv, acc)                                                     \
    {                                                                         \
        float e = __expf(-fabsf(xv));                                         \
        float inv = __builtin_amdgcn_rcpf(1.f + e);                           \
        acc += (xv >= 0.f) ? inv : e * inv;                                   \
        bce += fmaxf(xv, 0.f) - xv * yv + __logf(1.f + e);                    \
    }

__global__ __launch_bounds__(256) void fused_k(const float* __restrict__ logits,
                                               const float* __restrict__ dense_out,
                                               const int*   __restrict__ target,
                                               const float* __restrict__ dense_labels,
                                               float* __restrict__ out,
                                               double* __restrict__ loss1,
                                               double* __restrict__ loss2) {
    int bx = blockIdx.x;
    int t  = threadIdx.x;
    int wave = t >> 6;
    int lane = t & 63;

    __shared__ int   sidx[MAXN];
    __shared__ int   s_n;
    __shared__ float red[4];

    if (bx < MAIN_BLOCKS) {
        // ---------------- main path: one (class, 1024-d chunk) per block ----
        int c     = bx >> 2;
        int chunk = bx & 3;
        int d     = chunk * 1024 + (t << 2);

        if (t == 0) s_n = 0;
        __syncthreads();

        // scan all targets (32 KB, L2-resident) and compact class-c samples
        const int4* tp = (const int4*)target;
        #pragma unroll
        for (int k = 0; k < 8; ++k) {
            int4 v = tp[k * 256 + t];
            int s0 = (k * 256 + t) * 4;
            if (v.x == c) { int p = atomicAdd(&s_n, 1); sidx[p] = s0;     }
            if (v.y == c) { int p = atomicAdd(&s_n, 1); sidx[p] = s0 + 1; }
            if (v.z == c) { int p = atomicAdd(&s_n, 1); sidx[p] = s0 + 2; }
            if (v.w == c) { int p = atomicAdd(&s_n, 1); sidx[p] = s0 + 3; }
        }
        __syncthreads();
        int n = s_n;

        float4 y = *(const float4*)(dense_labels + (size_t)c * DD + d);
        float a0 = 0.f, a1 = 0.f, a2 = 0.f, a3 = 0.f, bce = 0.f;
        const float* dp = dense_out + d;

        // batches of 8 samples: all 8 float4 loads issued before consumption
        for (int base = 0; base < n; base += 8) {
            int m = n - base; if (m > 8) m = 8;
            float4 xb[8];
            #pragma unroll
            for (int j = 0; j < 8; ++j)
                if (j < m) xb[j] = *(const float4*)(dp + (size_t)sidx[base + j] * DD);
            #pragma unroll
            for (int j = 0; j < 8; ++j)
                if (j < m) {
                    ACC1(xb[j].x, y.x, a0) ACC1(xb[j].y, y.y, a1)
                    ACC1(xb[j].z, y.z, a2) ACC1(xb[j].w, y.w, a3)
                }
        }

        // out+1 is the [NC,DD] segment-sum (4B-aligned only -> dword stores)
        float* p = out + 1 + (size_t)c * DD + d;
        p[0] = a0; p[1] = a1; p[2] = a2; p[3] = a3;

        if (chunk == 0 && t == 0) out[1 + (size_t)NC * DD + c] = (float)n;

        #pragma unroll
        for (int o2 = 32; o2 > 0; o2 >>= 1) bce += __shfl_xor(bce, o2);
        if (lane == 0) red[wave] = bce;
        __syncthreads();
        if (t == 0)
            atomicAdd(&loss2[bx & (NSLOT - 1)],
                      (double)(red[0] + red[1] + red[2] + red[3]));
    } else {
        // ---------------- CE path: 4 waves/block, one sample per wave ------
        int i = (bx - MAIN_BLOCKS) * 4 + wave;
        const float* row = logits + (size_t)i * NC;
        int j0 = lane * 4;

        float4 r0 = *(const float4*)(row + j0);
        float4 r1 = *(const float4*)(row + j0 + 256);
        float4 r2 = *(const float4*)(row + j0 + 512);
        float4 r3;
        if (j0 + 768 < NC) r3 = *(const float4*)(row + j0 + 768);
        else r3 = make_float4(-INFINITY, -INFINITY, -INFINITY, -INFINITY);
        float tl = row[target[i]];

        float mx = fmaxf(fmaxf(fmaxf(r0.x, r0.y), fmaxf(r0.z, r0.w)),
                         fmaxf(fmaxf(r1.x, r1.y), fmaxf(r1.z, r1.w)));
        mx = fmaxf(mx, fmaxf(fmaxf(r2.x, r2.y), fmaxf(r2.z, r2.w)));
        mx = fmaxf(mx, fmaxf(fmaxf(r3.x, r3.y), fmaxf(r3.z, r3.w)));
        #pragma unroll
        for (int o = 32; o > 0; o >>= 1) mx = fmaxf(mx, __shfl_xor(mx, o));

        float s = __expf(r0.x - mx) + __expf(r0.y - mx) + __expf(r0.z - mx) + __expf(r0.w - mx)
                + __expf(r1.x - mx) + __expf(r1.y - mx) + __expf(r1.z - mx) + __expf(r1.w - mx)
                + __expf(r2.x - mx) + __expf(r2.y - mx) + __expf(r2.z - mx) + __expf(r2.w - mx)
                + __expf(r3.x - mx) + __expf(r3.y - mx) + __expf(r3.z - mx) + __expf(r3.w - mx);
        #pragma unroll
        for (int o = 32; o > 0; o >>= 1) s += __shfl_xor(s, o);

        if (lane == 0) red[wave] = -(tl - mx - __logf(s));
        __syncthreads();
        if (t == 0)
            atomicAdd(&loss1[bx & (NSLOT - 1)],
                      (double)(red[0] + red[1] + red[2] + red[3]));
    }
}

__global__ void fin_k(const double* __restrict__ loss1,
                      const double* __restrict__ loss2,
                      float* __restrict__ out) {
    double l1 = 0.0, l2 = 0.0;
    #pragma unroll
    for (int i = 0; i < NSLOT; ++i) { l1 += loss1[i]; l2 += loss2[i]; }
    out[0] = (float)(0.5 * (l1 / (double)BB) +
                     0.5 * (l2 / ((double)BB * (double)DD)));
}

extern "C" void kernel_launch(void* const* d_in, const int* in_sizes, int n_in,
                              void* d_out, int out_size, void* d_ws, size_t ws_size,
                              hipStream_t stream) {
    const float* logits       = (const float*)d_in[0];
    const float* dense_out    = (const float*)d_in[1];
    const int*   target       = (const int*)d_in[2];
    const float* dense_labels = (const float*)d_in[3];
    float* out = (float*)d_out;

    char* ws = (char*)d_ws;
    double* loss1 = (double*)(ws + 0);
    double* loss2 = (double*)(ws + 256);

    hipMemsetAsync(d_ws, 0, 512, stream);

    fused_k<<<TOT_BLOCKS, 256, 0, stream>>>(logits, dense_out, target,
                                            dense_labels, out, loss1, loss2);
    fin_k<<<1, 1, 0, stream>>>(loss1, loss2, out);
}